// Round 4
// baseline (185.446 us; speedup 1.0000x reference)
//
#include <hip/hip_runtime.h>

// ---- problem constants ----
#define Bb 32     // batch
#define NN 1024   // H*W = K dim = output cols per channel
#define CC 128    // channels
#define MT 128    // m-cols per block (4 waves x 32)

typedef __bf16 bf16x8 __attribute__((ext_vector_type(8)));
typedef float f32x16 __attribute__((ext_vector_type(16)));
typedef float f32x4 __attribute__((ext_vector_type(4)));
typedef unsigned short u16x8 __attribute__((ext_vector_type(8)));

// ---------------------------------------------------------------------------
// Pre-pass: inputs [B, N, C] fp32 -> xbf [C, B, N] bf16 (coalesced both sides
// via LDS tile). 512 blocks = 32 b x 16 n-tiles of 64.
// ---------------------------------------------------------------------------
__global__ __launch_bounds__(256) void transpose_x(const float* __restrict__ in,
                                                   __bf16* __restrict__ xbf) {
    __shared__ float tile[64 * 132];  // 64 n x 128 c, row padded to 132 floats
    const int b  = blockIdx.x >> 4;
    const int n0 = (blockIdx.x & 15) << 6;
    const int t  = threadIdx.x;

#pragma unroll
    for (int p = 0; p < 8; ++p) {
        int f     = p * 256 + t;
        int n_off = f >> 5;
        int c4    = (f & 31) << 2;
        f32x4 v = *reinterpret_cast<const f32x4*>(in + ((size_t)(b * NN + n0 + n_off) * CC + c4));
        *reinterpret_cast<f32x4*>(&tile[n_off * 132 + c4]) = v;
    }
    __syncthreads();

    const int c = t >> 1, half = t & 1;
    const size_t obase = ((size_t)c * Bb + b) * NN + n0;
#pragma unroll
    for (int q = 0; q < 4; ++q) {
        int nb = half * 32 + q * 8;
        bf16x8 o;
#pragma unroll
        for (int j = 0; j < 8; ++j) o[j] = (__bf16)tile[(nb + j) * 132 + c];
        *reinterpret_cast<bf16x8*>(xbf + obase + nb) = o;
    }
}

// ---------------------------------------------------------------------------
// Main GEMM — NO LDS, NO BARRIERS.
// Block = (channel c, m-tile of 128), 4 waves, wave owns 32 m-cols.
// mfma_f32_32x32x16_bf16 B-fragment: lane holds W[k0+lh*8+e][m=lane&31] for
// e=0..7 -> per e the wave reads 128B contiguous = coalesced global dwords.
// A-fragment: lane reads 16B contiguous from xbf[c][b=lane&31][k..]. No data
// sharing between lanes => no LDS, no sync; compiler pipelines loads freely
// and waves never stall on a collective vmcnt(0) drain.
// ---------------------------------------------------------------------------
template <int USE_XBF>
__global__ __launch_bounds__(256) void cwdense(const float* __restrict__ W,
                                               const float* __restrict__ bias,
                                               const float* __restrict__ xin,
                                               const __bf16* __restrict__ xbf,
                                               float* __restrict__ out) {
    // XCD-friendly mapping: XCD x handles c in [16x,16x+16). The 16 blocks
    // writing one 64B output line (same b,m, co group of 16) share an XCD L2
    // and are dispatched adjacently -> partial writes merge before writeback.
    const int x     = blockIdx.x;
    const int xcd   = x & 7;
    const int i     = x >> 3;
    const int c     = xcd * 16 + (i & 15);
    const int mtile = i >> 4;
    const int m0    = mtile * MT;

    const int t    = threadIdx.x;
    const int w    = t >> 6;
    const int lane = t & 63;
    const int lm   = lane & 31;   // A row (b) / B col (m) within 32x32 tile
    const int lh   = lane >> 5;   // k half: e covers k0+lh*8 .. +7
    const int m    = m0 + w * 32 + lm;

    // column base: W[c][lh*8][m]; element e,k0 at byte offset (k0+e)*4096
    const float*  wcol = W + (size_t)c * NN * NN + (size_t)(lh * 8) * NN + m;
    const __bf16* xrow = USE_XBF ? (xbf + ((size_t)c * Bb + lm) * NN + lh * 8) : nullptr;

    f32x16 acc;
#pragma unroll
    for (int r = 0; r < 16; ++r) acc[r] = 0.0f;

#pragma unroll 4
    for (int k0 = 0; k0 < NN; k0 += 16) {
        float wv[8];
#pragma unroll
        for (int e = 0; e < 8; ++e)
            wv[e] = wcol[(size_t)(k0 + e) * NN];

        bf16x8 a;
        if (USE_XBF) {
            a = *reinterpret_cast<const bf16x8*>(xrow + k0);
        } else {
            u16x8 tmp;
#pragma unroll
            for (int e = 0; e < 8; ++e) {
                float f = xin[((size_t)lm * NN + (k0 + lh * 8 + e)) * CC + c];
                unsigned u = __builtin_bit_cast(unsigned, f);
                u = (u + 0x7FFFu + ((u >> 16) & 1u)) >> 16;
                tmp[e] = (unsigned short)u;
            }
            a = __builtin_bit_cast(bf16x8, tmp);
        }

        bf16x8 bfrag;
#pragma unroll
        for (int e = 0; e < 8; ++e) bfrag[e] = (__bf16)wv[e];  // fuses to v_cvt_pk_bf16_f32

        acc = __builtin_amdgcn_mfma_f32_32x32x16_bf16(a, bfrag, acc, 0, 0, 0);
    }

    // epilogue: bias + relu + store. out[b][m][co], co = 127 - c.
    const float bv = bias[(size_t)c * NN + m];
    const int co = (CC - 1) - c;
#pragma unroll
    for (int r = 0; r < 16; ++r) {
        const int brow = (r & 3) + 8 * (r >> 2) + 4 * lh;
        float v = acc[r] + bv;
        v = v > 0.0f ? v : 0.0f;
        out[(size_t)brow * (NN * CC) + (size_t)m * CC + co] = v;
    }
}

extern "C" void kernel_launch(void* const* d_in, const int* in_sizes, int n_in,
                              void* d_out, int out_size, void* d_ws, size_t ws_size,
                              hipStream_t stream) {
    const float* xinp = (const float*)d_in[0];
    const float* W    = (const float*)d_in[1];
    const float* bias = (const float*)d_in[2];
    float* out        = (float*)d_out;

    const size_t need = (size_t)CC * Bb * NN * sizeof(__bf16);  // 8 MB
    if (ws_size >= need) {
        __bf16* xbf = (__bf16*)d_ws;
        transpose_x<<<512, 256, 0, stream>>>(xinp, xbf);
        cwdense<1><<<1024, 256, 0, stream>>>(W, bias, xinp, xbf, out);
    } else {
        cwdense<0><<<1024, 256, 0, stream>>>(W, bias, xinp, nullptr, out);
    }
}